// Round 9
// baseline (76.468 us; speedup 1.0000x reference)
//
#include <hip/hip_runtime.h>
#include <cstdint>
#include <cmath>

#define D_DIM 2048
#define E_DIM 64
#define N_TOK 16384
#define K_TOP 8
#define KSTEP 32
#define TSTEPS 16      // k-steps per wave = 512 / 32
#define NFRAG 12       // 4 etiles x 3 terms

typedef __attribute__((ext_vector_type(8))) short bf16x8;
typedef __attribute__((ext_vector_type(4))) float f32x4;

union U4 { uint4 u; bf16x8 s; };

// round-to-nearest bf16 3-way split: x = h + m + l + r, |r| ~ 2^-23 |x|
__device__ inline void split3_8(const float* a8, bf16x8& h, bf16x8& m, bf16x8& l) {
#pragma unroll
  for (int j = 0; j < 8; ++j) {
    const float x = a8[j];
    const unsigned u = __builtin_bit_cast(unsigned, x);
    const unsigned rh = (u + 0x7FFFu + ((u >> 16) & 1u)) & 0xFFFF0000u;
    h[j] = (short)(rh >> 16);
    const float r1 = x - __builtin_bit_cast(float, rh);
    const unsigned u1 = __builtin_bit_cast(unsigned, r1);
    const unsigned rm = (u1 + 0x7FFFu + ((u1 >> 16) & 1u)) & 0xFFFF0000u;
    m[j] = (short)(rm >> 16);
    const float r2 = r1 - __builtin_bit_cast(float, rm);
    l[j] = (short)(__builtin_bit_cast(unsigned, r2) >> 16);
  }
}

// Kernel 1: pre-split W into 3-term MFMA B-fragments.
// WF[(ks*12 + et*3 + term)*64 + lane]; lane holds W[et*16+(l&15)][ks*32+(l>>4)*8+j]
__global__ void wprep_kernel(const float* __restrict__ W, uint4* __restrict__ WF) {
  const int gid = blockIdx.x * 256 + threadIdx.x;
  const int lane = gid & 63;
  const int et = (gid >> 6) & 3;
  const int ks = gid >> 8;
  const int e = et * 16 + (lane & 15);
  const int kg = lane >> 4;
  const float* src = W + (size_t)e * D_DIM + ks * KSTEP + kg * 8;
  const float4 a = ((const float4*)src)[0];
  const float4 b = ((const float4*)src)[1];
  float a8[8] = {a.x, a.y, a.z, a.w, b.x, b.y, b.z, b.w};
  U4 h, m, l;
  split3_8(a8, h.s, m.s, l.s);
  const int fbase = (ks * NFRAG + et * 3) * 64 + lane;
  WF[fbase] = h.u;
  WF[fbase + 64] = m.u;
  WF[fbase + 128] = l.u;
}

#define BCV(x) __builtin_bit_cast(bf16x8, x)
#define MM(d, A, B) d = __builtin_amdgcn_mfma_f32_16x16x32_bf16(A, BCV(B), d, 0, 0, 0)

#define SPLIT3V(v0, v1, H, M, L)                                     \
  do {                                                               \
    float a8_[8] = {v0.x, v0.y, v0.z, v0.w, v1.x, v1.y, v1.z, v1.w}; \
    split3_8(a8_, H, M, L);                                          \
  } while (0)

// ---------------- PATH 1: 2048 single-wave blocks -> partials, then reduce ----------------

// Kernel A: one wave per block. M=32 tokens, K-slice=512, all 64 experts.
// B-frags in two 6-frag half-sets (consume then prefetch) to fit <=170 regs.
__global__ __launch_bounds__(64, 3)
void gemm_partial(const float* __restrict__ X, const uint4* __restrict__ WF,
                  float* __restrict__ Part) {
  const int bid = blockIdx.x;   // 2048
  const int ks = bid & 3;       // k-slice
  const int mt = bid >> 2;      // 0..511 token tile (32 tokens)
  const int l = threadIdx.x;
  const int col = l & 15;
  const int kg = l >> 4;
  const int tok0 = mt * 32;

  const float* gX0 = X + (size_t)(tok0 + col) * D_DIM + ks * (TSTEPS * KSTEP) + kg * 8;
  const float* gX1 = gX0 + (size_t)16 * D_DIM;
  const uint4* gB = WF + (size_t)ks * TSTEPS * (NFRAG * 64) + l;

  f32x4 acc0[8], acc1[8];  // [mt2*4+et]
#pragma unroll
  for (int i = 0; i < 8; ++i) { acc0[i] = (f32x4)0.f; acc1[i] = (f32x4)0.f; }

  float4 x00, x01, x10, x11;
  uint4 bA[6], bB[6];  // half-sets: etiles {0,1} and {2,3}

#define LOAD_X(t)                         \
  do {                                    \
    const float* p0_ = gX0 + (t) * KSTEP; \
    const float* p1_ = gX1 + (t) * KSTEP; \
    x00 = *(const float4*)p0_;            \
    x01 = *(const float4*)(p0_ + 4);      \
    x10 = *(const float4*)p1_;            \
    x11 = *(const float4*)(p1_ + 4);      \
  } while (0)

#define LOAD_BA(t)                                      \
  do {                                                  \
    const uint4* bp_ = gB + (size_t)(t) * (NFRAG * 64); \
    bA[0] = bp_[0 * 64]; bA[1] = bp_[1 * 64];           \
    bA[2] = bp_[2 * 64]; bA[3] = bp_[3 * 64];           \
    bA[4] = bp_[4 * 64]; bA[5] = bp_[5 * 64];           \
  } while (0)

#define LOAD_BB(t)                                      \
  do {                                                  \
    const uint4* bp_ = gB + (size_t)(t) * (NFRAG * 64); \
    bB[0] = bp_[6 * 64];  bB[1] = bp_[7 * 64];          \
    bB[2] = bp_[8 * 64];  bB[3] = bp_[9 * 64];          \
    bB[4] = bp_[10 * 64]; bB[5] = bp_[11 * 64];         \
  } while (0)

  // 24 MFMA per half: etiles BASE+0, BASE+1, both mtiles, 6 products.
  // Grouped by term so dependent acc1 ops have 4-wide interleave.
#define CRUNCH_HALF(BARR, BASE, AH0, AM0, AL0, AH1, AM1, AL1)          \
  do {                                                                 \
    _Pragma("unroll") for (int e2 = 0; e2 < 2; ++e2) {                 \
      MM(acc0[BASE + e2], AH0, BARR[e2 * 3]);                          \
      MM(acc0[4 + BASE + e2], AH1, BARR[e2 * 3]);                      \
    }                                                                  \
    _Pragma("unroll") for (int e2 = 0; e2 < 2; ++e2) {                 \
      MM(acc1[BASE + e2], AH0, BARR[e2 * 3 + 1]);                      \
      MM(acc1[4 + BASE + e2], AH1, BARR[e2 * 3 + 1]);                  \
    }                                                                  \
    _Pragma("unroll") for (int e2 = 0; e2 < 2; ++e2) {                 \
      MM(acc1[BASE + e2], AM0, BARR[e2 * 3]);                          \
      MM(acc1[4 + BASE + e2], AM1, BARR[e2 * 3]);                      \
    }                                                                  \
    _Pragma("unroll") for (int e2 = 0; e2 < 2; ++e2) {                 \
      MM(acc1[BASE + e2], AH0, BARR[e2 * 3 + 2]);                      \
      MM(acc1[4 + BASE + e2], AH1, BARR[e2 * 3 + 2]);                  \
    }                                                                  \
    _Pragma("unroll") for (int e2 = 0; e2 < 2; ++e2) {                 \
      MM(acc1[BASE + e2], AL0, BARR[e2 * 3]);                          \
      MM(acc1[4 + BASE + e2], AL1, BARR[e2 * 3]);                      \
    }                                                                  \
    _Pragma("unroll") for (int e2 = 0; e2 < 2; ++e2) {                 \
      MM(acc1[BASE + e2], AM0, BARR[e2 * 3 + 1]);                      \
      MM(acc1[4 + BASE + e2], AM1, BARR[e2 * 3 + 1]);                  \
    }                                                                  \
  } while (0)

  LOAD_X(0);
  LOAD_BA(0);
  LOAD_BB(0);

#pragma unroll 1
  for (int t = 0; t < TSTEPS; ++t) {
    bf16x8 ah0, am0, al0, ah1, am1, al1;
    SPLIT3V(x00, x01, ah0, am0, al0);
    SPLIT3V(x10, x11, ah1, am1, al1);
    if (t + 1 < TSTEPS) LOAD_X(t + 1);  // WAR-safe: issued after split's reads
    __builtin_amdgcn_sched_barrier(0);
    CRUNCH_HALF(bA, 0, ah0, am0, al0, ah1, am1, al1);
    if (t + 1 < TSTEPS) LOAD_BA(t + 1);
    __builtin_amdgcn_sched_barrier(0);
    CRUNCH_HALF(bB, 2, ah0, am0, al0, ah1, am1, al1);
    if (t + 1 < TSTEPS) LOAD_BB(t + 1);
    __builtin_amdgcn_sched_barrier(0);
  }

  // write partials: Part[ks][tok][e]; C/D layout col=lane&15, row=(lane>>4)*4+q
#pragma unroll
  for (int mt2 = 0; mt2 < 2; ++mt2)
#pragma unroll
    for (int q = 0; q < 4; ++q) {
      const int tok = tok0 + mt2 * 16 + kg * 4 + q;
      float* dst = Part + ((size_t)ks * N_TOK + tok) * E_DIM + col;
#pragma unroll
      for (int et = 0; et < 4; ++et)
        dst[et * 16] = acc0[mt2 * 4 + et][q] + acc1[mt2 * 4 + et][q];
    }
}

// Kernel B: fixed-order 4-way reduce + validated ballot top-8 + softmax + scatter.
__global__ __launch_bounds__(256)
void reduce_router(const float* __restrict__ Part,
                   float* __restrict__ Pout, float* __restrict__ Mout) {
  const int lane = threadIdx.x & 63;
  const int gw = blockIdx.x * 4 + (threadIdx.x >> 6);  // 2048 waves

#pragma unroll 1
  for (int j = 0; j < 8; ++j) {
    const int tok = gw * 8 + j;
    const size_t base = (size_t)tok * E_DIM + lane;
    float v = Part[base];
    v += Part[(size_t)1 * N_TOK * E_DIM + base];
    v += Part[(size_t)2 * N_TOK * E_DIM + base];
    v += Part[(size_t)3 * N_TOK * E_DIM + base];

    float topv[K_TOP];
    int topi[K_TOP];
#pragma unroll
    for (int kk = 0; kk < K_TOP; ++kk) {
      float m = v;
#pragma unroll
      for (int off = 32; off > 0; off >>= 1)
        m = fmaxf(m, __shfl_xor(m, off, 64));
      const unsigned long long bal = __ballot(v == m);
      const int li = __ffsll(bal) - 1;  // lowest expert on ties == jax stable order
      topv[kk] = m;
      topi[kk] = li;
      if (lane == li) v = -INFINITY;
    }

    float p[K_TOP], sum = 0.f;
#pragma unroll
    for (int kk = 0; kk < K_TOP; ++kk) {
      p[kk] = expf(topv[kk] - topv[0]);
      sum += p[kk];
    }
    const float inv = 1.f / sum;

    float pv = 0.f, mv = 0.f;
#pragma unroll
    for (int kk = 0; kk < K_TOP; ++kk)
      if (topi[kk] == lane) { pv = p[kk] * inv; mv = 1.f; }

    Pout[(size_t)tok * E_DIM + lane] = pv;
    Mout[(size_t)tok * E_DIM + lane] = mv;
  }
}

// ---------------- PATH 2 (fallback if ws too small): round-8 kernel ----------------

__global__ __launch_bounds__(256, 2)
void gemm_router_fb(const float* __restrict__ X, const uint4* __restrict__ WF,
                    float* __restrict__ Pout, float* __restrict__ Mout) {
  __shared__ float red[2][4][64][17];

  const int tid = threadIdx.x;
  const int w = tid >> 6;
  const int l = tid & 63;
  const int col = l & 15;
  const int kg = l >> 4;
  const int tok0 = blockIdx.x * 32;

  const float* gX0 = X + (size_t)(tok0 + col) * D_DIM + w * (TSTEPS * KSTEP) + kg * 8;
  const float* gX1 = gX0 + (size_t)16 * D_DIM;
  const uint4* gB = WF + (size_t)w * TSTEPS * (NFRAG * 64) + l;

  f32x4 acc0[8], acc1[8];
#pragma unroll
  for (int i = 0; i < 8; ++i) { acc0[i] = (f32x4)0.f; acc1[i] = (f32x4)0.f; }

  float4 x00, x01, x10, x11;
  uint4 bA[6], bB[6];

  LOAD_X(0);
  LOAD_BA(0);
  LOAD_BB(0);

#pragma unroll 1
  for (int t = 0; t < TSTEPS; ++t) {
    bf16x8 ah0, am0, al0, ah1, am1, al1;
    SPLIT3V(x00, x01, ah0, am0, al0);
    SPLIT3V(x10, x11, ah1, am1, al1);
    if (t + 1 < TSTEPS) LOAD_X(t + 1);
    __builtin_amdgcn_sched_barrier(0);
    CRUNCH_HALF(bA, 0, ah0, am0, al0, ah1, am1, al1);
    if (t + 1 < TSTEPS) LOAD_BA(t + 1);
    __builtin_amdgcn_sched_barrier(0);
    CRUNCH_HALF(bB, 2, ah0, am0, al0, ah1, am1, al1);
    if (t + 1 < TSTEPS) LOAD_BB(t + 1);
    __builtin_amdgcn_sched_barrier(0);
  }

#pragma unroll
  for (int mt2 = 0; mt2 < 2; ++mt2)
#pragma unroll
    for (int et = 0; et < 4; ++et)
#pragma unroll
      for (int q = 0; q < 4; ++q)
        red[mt2][w][l][et * 4 + q] = acc0[mt2 * 4 + et][q] + acc1[mt2 * 4 + et][q];

  __syncthreads();
  if (w >= 2) return;

  float fin[16];
#pragma unroll
  for (int i = 0; i < 16; ++i) {
    float s = red[w][0][l][i];
    s += red[w][1][l][i];
    s += red[w][2][l][i];
    s += red[w][3][l][i];
    fin[i] = s;
  }

#pragma unroll
  for (int q = 0; q < 4; ++q) {
    float v[4];
#pragma unroll
    for (int et = 0; et < 4; ++et) v[et] = fin[et * 4 + q];

    float topv[K_TOP];
    int topi[K_TOP];
#pragma unroll
    for (int t = 0; t < K_TOP; ++t) {
      float bv = v[0];
      int bi = col;
#pragma unroll
      for (int et = 1; et < 4; ++et) {
        const bool take = v[et] > bv;
        bv = take ? v[et] : bv;
        bi = take ? (et * 16 + col) : bi;
      }
#pragma unroll
      for (int off = 1; off < 16; off <<= 1) {
        const float ov = __shfl_xor(bv, off, 64);
        const int oi = __shfl_xor(bi, off, 64);
        const bool take = (ov > bv) || (ov == bv && oi < bi);
        bv = take ? ov : bv;
        bi = take ? oi : bi;
      }
      topv[t] = bv;
      topi[t] = bi;
#pragma unroll
      for (int et = 0; et < 4; ++et)
        if (bi == et * 16 + col) v[et] = -INFINITY;
    }

    float p[K_TOP], sum = 0.f;
#pragma unroll
    for (int t = 0; t < K_TOP; ++t) {
      p[t] = expf(topv[t] - topv[0]);
      sum += p[t];
    }
    const float inv = 1.f / sum;

    const int tok = tok0 + w * 16 + kg * 4 + q;
#pragma unroll
    for (int et = 0; et < 4; ++et) {
      const int e = et * 16 + col;
      float pv = 0.f, mv = 0.f;
#pragma unroll
      for (int t = 0; t < K_TOP; ++t) {
        const bool hit = (topi[t] == e);
        pv = hit ? p[t] * inv : pv;
        mv = hit ? 1.f : mv;
      }
      Pout[(size_t)tok * E_DIM + e] = pv;
      Mout[(size_t)tok * E_DIM + e] = mv;
    }
  }
}

extern "C" void kernel_launch(void* const* d_in, const int* in_sizes, int n_in,
                              void* d_out, int out_size, void* d_ws, size_t ws_size,
                              hipStream_t stream) {
  const float* X = (const float*)d_in[0];
  const float* W = (const float*)d_in[1];
  float* P = (float*)d_out;
  float* M = P + (size_t)N_TOK * E_DIM;

  uint4* WF = (uint4*)d_ws;                                   // 768 KB at offset 0
  float* Part = (float*)((char*)d_ws + (size_t)(1 << 20));    // 16 MB at offset 1MB
  const size_t needed = (size_t)(1 << 20) + (size_t)4 * N_TOK * E_DIM * sizeof(float);

  wprep_kernel<<<dim3(64), dim3(256), 0, stream>>>(W, WF);
  if (ws_size >= needed) {
    gemm_partial<<<dim3(2048), dim3(64), 0, stream>>>(X, WF, Part);
    reduce_router<<<dim3(512), dim3(256), 0, stream>>>(Part, P, M);
  } else {
    gemm_router_fb<<<dim3(512), dim3(256), 0, stream>>>(X, WF, P, M);
  }
}

// Round 10
// 62.066 us; speedup vs baseline: 1.2320x; 1.2320x over previous
//
#include <hip/hip_runtime.h>
#include <cstdint>
#include <cmath>

#define D_DIM 2048
#define E_DIM 64
#define N_TOK 16384
#define K_TOP 8
#define KSTEP 32
#define TSTEPS 16      // k-steps per K-slice = 512 / 32
#define NFRAG 12       // 4 etiles x 3 terms

typedef __attribute__((ext_vector_type(8))) short bf16x8;
typedef __attribute__((ext_vector_type(4))) float f32x4;
typedef __attribute__((ext_vector_type(4))) unsigned u32x4;

// round-to-nearest bf16 3-way split: x = h + m + l + r, |r| ~ 2^-23 |x|
__device__ inline void split3(const f32x4 v0, const f32x4 v1,
                              bf16x8& h, bf16x8& m, bf16x8& l) {
#pragma unroll
  for (int j = 0; j < 8; ++j) {
    const float x = (j < 4) ? v0[j] : v1[j - 4];
    const unsigned u = __builtin_bit_cast(unsigned, x);
    const unsigned rh = (u + 0x7FFFu + ((u >> 16) & 1u)) & 0xFFFF0000u;
    h[j] = (short)(rh >> 16);
    const float r1 = x - __builtin_bit_cast(float, rh);
    const unsigned u1 = __builtin_bit_cast(unsigned, r1);
    const unsigned rm = (u1 + 0x7FFFu + ((u1 >> 16) & 1u)) & 0xFFFF0000u;
    m[j] = (short)(rm >> 16);
    const float r2 = r1 - __builtin_bit_cast(float, rm);
    l[j] = (short)(__builtin_bit_cast(unsigned, r2) >> 16);
  }
}

// Kernel 1: pre-split W into 3-term MFMA B-fragments.
// WF[(ks*12 + et*3 + term)*64 + lane]; lane holds W[et*16+(l&15)][ks*32+(l>>4)*8+j]
__global__ void wprep_kernel(const float* __restrict__ W, uint4* __restrict__ WF) {
  const int gid = blockIdx.x * 256 + threadIdx.x;
  const int lane = gid & 63;
  const int et = (gid >> 6) & 3;
  const int ks = gid >> 8;
  const int e = et * 16 + (lane & 15);
  const int kg = lane >> 4;
  const float* src = W + (size_t)e * D_DIM + ks * KSTEP + kg * 8;
  const f32x4 a = *(const f32x4*)src;
  const f32x4 b = *(const f32x4*)(src + 4);
  bf16x8 h, m, l;
  split3(a, b, h, m, l);
  const int fbase = (ks * NFRAG + et * 3) * 64 + lane;
  WF[fbase] = __builtin_bit_cast(uint4, h);
  WF[fbase + 64] = __builtin_bit_cast(uint4, m);
  WF[fbase + 128] = __builtin_bit_cast(uint4, l);
}

#define BCV(x) __builtin_bit_cast(bf16x8, x)
#define MM(d, A, B) d = __builtin_amdgcn_mfma_f32_16x16x32_bf16(A, BCV(B), d, 0, 0, 0)

// forced-register global load: SGPR base + VGPR offset + imm
#define GL4(dst, voff, sbase, IMM)                              \
  asm volatile("global_load_dwordx4 %0, %1, %2 offset:" #IMM    \
               : "=v"(dst) : "v"(voff), "s"(sbase) : "memory")

#define SB0 __builtin_amdgcn_sched_barrier(0)
#define WAITV(N) asm volatile("s_waitcnt vmcnt(" #N ")" ::: "memory")

// Kernel A: one wave per block (2048 blocks). M=32 tokens, K-slice=512.
// ALL main-loop loads are inline-asm (16 per step: 12 B + 4 X), issued 2 steps
// ahead into ping-pong register sets; counted vmcnt(16) per phase.
__global__ __launch_bounds__(64, 2)
void gemm_partial(const float* __restrict__ X, const uint4* __restrict__ WF,
                  float* __restrict__ Part) {
  const int bid = blockIdx.x;   // 2048
  const int ks = bid & 3;       // k-slice
  const int mt = bid >> 2;      // token tile (32 tokens)
  const int l = threadIdx.x;
  const int col = l & 15;
  const int kg = l >> 4;
  const int tok0 = mt * 32;

  // uniform byte bases (SGPR), advanced by compile-time multiples of step
  const char* sB = (const char*)WF + (size_t)(ks * TSTEPS) * 12288;
  const char* sX = (const char*)X + (size_t)tok0 * 8192 + (size_t)ks * 2048;

  // per-lane 32-bit offsets (VGPR)
  const unsigned vB0 = (unsigned)(l * 16);
  const unsigned vB1 = vB0 + 4096;
  const unsigned vB2 = vB0 + 8192;
  const unsigned vX0 = (unsigned)(col * 8192 + kg * 32);
  const unsigned vX1 = vX0 + 16 * 8192;

  f32x4 acc0[8], acc1[8];  // [mt2*4+et]
#pragma unroll
  for (int i = 0; i < 8; ++i) { acc0[i] = (f32x4)0.f; acc1[i] = (f32x4)0.f; }

  u32x4 bE[NFRAG], bO[NFRAG];
  f32x4 xE[4], xO[4];

#define ISSUE_STEP(bS, xS, t)                          \
  do {                                                 \
    const char* sB_ = sB + (size_t)(t) * 12288;        \
    const char* sX_ = sX + (size_t)(t) * 128;          \
    GL4(bS[0], vB0, sB_, 0);                           \
    GL4(bS[1], vB0, sB_, 1024);                        \
    GL4(bS[2], vB0, sB_, 2048);                        \
    GL4(bS[3], vB0, sB_, 3072);                        \
    GL4(bS[4], vB1, sB_, 0);                           \
    GL4(bS[5], vB1, sB_, 1024);                        \
    GL4(bS[6], vB1, sB_, 2048);                        \
    GL4(bS[7], vB1, sB_, 3072);                        \
    GL4(bS[8], vB2, sB_, 0);                           \
    GL4(bS[9], vB2, sB_, 1024);                        \
    GL4(bS[10], vB2, sB_, 2048);                       \
    GL4(bS[11], vB2, sB_, 3072);                       \
    GL4(xS[0], vX0, sX_, 0);                           \
    GL4(xS[1], vX0, sX_, 16);                          \
    GL4(xS[2], vX1, sX_, 0);                           \
    GL4(xS[3], vX1, sX_, 16);                          \
  } while (0)

  // 48 MFMAs: frag f = et*3+term (0=h,1=m,2=l)
#define CRUNCH(bS, AH0, AM0, AL0, AH1, AM1, AL1)                                         \
  do {                                                                                   \
    _Pragma("unroll") for (int et = 0; et < 4; ++et) {                                   \
      MM(acc0[et], AH0, bS[et * 3]);     MM(acc0[4 + et], AH1, bS[et * 3]);              \
    }                                                                                    \
    _Pragma("unroll") for (int et = 0; et < 4; ++et) {                                   \
      MM(acc1[et], AH0, bS[et * 3 + 1]); MM(acc1[4 + et], AH1, bS[et * 3 + 1]);          \
    }                                                                                    \
    _Pragma("unroll") for (int et = 0; et < 4; ++et) {                                   \
      MM(acc1[et], AM0, bS[et * 3]);     MM(acc1[4 + et], AM1, bS[et * 3]);              \
    }                                                                                    \
    _Pragma("unroll") for (int et = 0; et < 4; ++et) {                                   \
      MM(acc1[et], AH0, bS[et * 3 + 2]); MM(acc1[4 + et], AH1, bS[et * 3 + 2]);          \
    }                                                                                    \
    _Pragma("unroll") for (int et = 0; et < 4; ++et) {                                   \
      MM(acc1[et], AL0, bS[et * 3]);     MM(acc1[4 + et], AL1, bS[et * 3]);              \
    }                                                                                    \
    _Pragma("unroll") for (int et = 0; et < 4; ++et) {                                   \
      MM(acc1[et], AM0, bS[et * 3 + 1]); MM(acc1[4 + et], AM1, bS[et * 3 + 1]);          \
    }                                                                                    \
  } while (0)

#define PHASE(bS, xS)                                  \
  do {                                                 \
    bf16x8 ah0, am0, al0, ah1, am1, al1;               \
    split3(xS[0], xS[1], ah0, am0, al0);               \
    split3(xS[2], xS[3], ah1, am1, al1);               \
    CRUNCH(bS, ah0, am0, al0, ah1, am1, al1);          \
    SB0;                                               \
  } while (0)

  // prologue: 2 steps in flight (32 loads), wait for step 0
  ISSUE_STEP(bE, xE, 0);
  ISSUE_STEP(bO, xO, 1);
  WAITV(16);
  SB0;

#pragma unroll 1
  for (int t = 0; t < TSTEPS - 2; t += 2) {
    PHASE(bE, xE);               // consume step t
    ISSUE_STEP(bE, xE, t + 2);   // refill same parity set
    WAITV(16);                   // step t+1 data complete
    SB0;
    PHASE(bO, xO);               // consume step t+1
    ISSUE_STEP(bO, xO, t + 3);
    WAITV(16);                   // step t+2 data complete
    SB0;
  }
  // tail: steps 14, 15 (no more issues)
  PHASE(bE, xE);
  WAITV(0);
  SB0;
  PHASE(bO, xO);

  // write partials: Part[ks][tok][e]; C/D layout col=lane&15, row=(lane>>4)*4+q
#pragma unroll
  for (int mt2 = 0; mt2 < 2; ++mt2)
#pragma unroll
    for (int q = 0; q < 4; ++q) {
      const int tok = tok0 + mt2 * 16 + kg * 4 + q;
      float* dst = Part + ((size_t)ks * N_TOK + tok) * E_DIM + col;
#pragma unroll
      for (int et = 0; et < 4; ++et)
        dst[et * 16] = acc0[mt2 * 4 + et][q] + acc1[mt2 * 4 + et][q];
    }
}

// Kernel B: fixed-order 4-way reduce + validated ballot top-8 + softmax + scatter.
__global__ __launch_bounds__(256)
void reduce_router(const float* __restrict__ Part,
                   float* __restrict__ Pout, float* __restrict__ Mout) {
  const int lane = threadIdx.x & 63;
  const int gw = blockIdx.x * 4 + (threadIdx.x >> 6);  // 2048 waves

#pragma unroll 1
  for (int j = 0; j < 8; ++j) {
    const int tok = gw * 8 + j;
    const size_t base = (size_t)tok * E_DIM + lane;
    float v = Part[base];
    v += Part[(size_t)1 * N_TOK * E_DIM + base];
    v += Part[(size_t)2 * N_TOK * E_DIM + base];
    v += Part[(size_t)3 * N_TOK * E_DIM + base];

    float topv[K_TOP];
    int topi[K_TOP];
#pragma unroll
    for (int kk = 0; kk < K_TOP; ++kk) {
      float m = v;
#pragma unroll
      for (int off = 32; off > 0; off >>= 1)
        m = fmaxf(m, __shfl_xor(m, off, 64));
      const unsigned long long bal = __ballot(v == m);
      const int li = __ffsll(bal) - 1;  // lowest expert on ties == jax stable order
      topv[kk] = m;
      topi[kk] = li;
      if (lane == li) v = -INFINITY;
    }

    float p[K_TOP], sum = 0.f;
#pragma unroll
    for (int kk = 0; kk < K_TOP; ++kk) {
      p[kk] = expf(topv[kk] - topv[0]);
      sum += p[kk];
    }
    const float inv = 1.f / sum;

    float pv = 0.f, mv = 0.f;
#pragma unroll
    for (int kk = 0; kk < K_TOP; ++kk)
      if (topi[kk] == lane) { pv = p[kk] * inv; mv = 1.f; }

    Pout[(size_t)tok * E_DIM + lane] = pv;
    Mout[(size_t)tok * E_DIM + lane] = mv;
  }
}

extern "C" void kernel_launch(void* const* d_in, const int* in_sizes, int n_in,
                              void* d_out, int out_size, void* d_ws, size_t ws_size,
                              hipStream_t stream) {
  const float* X = (const float*)d_in[0];
  const float* W = (const float*)d_in[1];
  float* P = (float*)d_out;
  float* M = P + (size_t)N_TOK * E_DIM;

  uint4* WF = (uint4*)d_ws;                                 // 768 KB at offset 0
  float* Part = (float*)((char*)d_ws + (size_t)(1 << 20));  // 16 MB at offset 1 MB

  wprep_kernel<<<dim3(64), dim3(256), 0, stream>>>(W, WF);
  gemm_partial<<<dim3(2048), dim3(64), 0, stream>>>(X, WF, Part);
  reduce_router<<<dim3(512), dim3(256), 0, stream>>>(Part, P, M);
}

// Round 14
// 59.202 us; speedup vs baseline: 1.2916x; 1.0484x over previous
//
#include <hip/hip_runtime.h>
#include <cstdint>
#include <cmath>

#define D_DIM 2048
#define E_DIM 64
#define N_TOK 16384
#define K_TOP 8
#define KSTEP 32
#define TSTEPS 16      // k-steps per K-slice = 512 / 32
#define NFRAG 12       // 4 etiles x 3 terms

typedef __attribute__((ext_vector_type(8))) short bf16x8;
typedef __attribute__((ext_vector_type(4))) float f32x4;

// round-to-nearest bf16 3-way split: x = h + m + l + r, |r| ~ 2^-23 |x|
__device__ inline void split3(const f32x4 v0, const f32x4 v1,
                              bf16x8& h, bf16x8& m, bf16x8& l) {
#pragma unroll
  for (int j = 0; j < 8; ++j) {
    const float x = (j < 4) ? v0[j] : v1[j - 4];
    const unsigned u = __builtin_bit_cast(unsigned, x);
    const unsigned rh = (u + 0x7FFFu + ((u >> 16) & 1u)) & 0xFFFF0000u;
    h[j] = (short)(rh >> 16);
    const float r1 = x - __builtin_bit_cast(float, rh);
    const unsigned u1 = __builtin_bit_cast(unsigned, r1);
    const unsigned rm = (u1 + 0x7FFFu + ((u1 >> 16) & 1u)) & 0xFFFF0000u;
    m[j] = (short)(rm >> 16);
    const float r2 = r1 - __builtin_bit_cast(float, rm);
    l[j] = (short)(__builtin_bit_cast(unsigned, r2) >> 16);
  }
}

// Kernel 1: pre-split W into 3-term MFMA B-fragments.
// WF[(kstep*12 + et*3 + term)*64 + lane]; lane holds W[et*16+(l&15)][kstep*32+(l>>4)*8+j]
__global__ void wprep_kernel(const float* __restrict__ W, uint4* __restrict__ WF) {
  const int gid = blockIdx.x * 256 + threadIdx.x;
  const int lane = gid & 63;
  const int et = (gid >> 6) & 3;
  const int ks = gid >> 8;  // 0..63 global k-step
  const int e = et * 16 + (lane & 15);
  const int kg = lane >> 4;
  const float* src = W + (size_t)e * D_DIM + ks * KSTEP + kg * 8;
  const f32x4 a = *(const f32x4*)src;
  const f32x4 b = *(const f32x4*)(src + 4);
  bf16x8 h, m, l;
  split3(a, b, h, m, l);
  const int fbase = (ks * NFRAG + et * 3) * 64 + lane;
  WF[fbase] = __builtin_bit_cast(uint4, h);
  WF[fbase + 64] = __builtin_bit_cast(uint4, m);
  WF[fbase + 128] = __builtin_bit_cast(uint4, l);
}

#define BCV(x) __builtin_bit_cast(bf16x8, x)
#define MM(d, A, B) d = __builtin_amdgcn_mfma_f32_16x16x32_bf16(A, BCV(B), d, 0, 0, 0)

// forced-register global load: block-uniform SGPR base + per-lane VGPR offset + imm
#define GL4(dst, voff, sbase, IMM)                              \
  asm volatile("global_load_dwordx4 %0, %1, %2 offset:" #IMM    \
               : "=v"(dst) : "v"(voff), "s"(sbase) : "memory")

#define SB0 __builtin_amdgcn_sched_barrier(0)
#define WAITV(N) asm volatile("s_waitcnt vmcnt(" #N ")" ::: "memory")
#define FENCE asm volatile("" ::: "memory")
#define BAR __builtin_amdgcn_s_barrier()

// Kernel A: 512 blocks x 4 waves. Block = 128 tokens x K-slice 512.
// B staged once per block into LDS ring-4 via global_load_lds (3/wave/step),
// X per-wave asm ping-pong regs (4/step), 12 ds_read_b128 + 48 MFMA per step.
// Raw s_barrier + counted vmcnt(7) per step — loads stay in flight across barriers.
__global__ __launch_bounds__(256, 2)
void gemm_partial(const float* __restrict__ X, const uint4* __restrict__ WF,
                  float* __restrict__ Part) {
  __shared__ uint4 ldsB[4][NFRAG][64];  // 48 KB ring

  const int bid = blockIdx.x;   // 512
  const int ks = bid & 3;       // k-slice
  const int mtile = bid >> 2;   // 0..127 : 128-token tile
  const int tid = threadIdx.x;
  const int w = tid >> 6;
  const int l = tid & 63;
  const int col = l & 15;
  const int kg = l >> 4;
  const int tokw = mtile * 128 + w * 32;  // this wave's 32 tokens

  // BLOCK-uniform base (SGPR-provable: blockIdx-derived only)
  const char* sX = (const char*)X + (size_t)(mtile * 128) * 8192 + (size_t)ks * 2048;
  const char* wfB = (const char*)WF + (size_t)ks * TSTEPS * 12288;

  // per-lane 32-bit offsets (VGPR) — wave offset folded in here
  const unsigned vX0 = (unsigned)(w * 32 * 8192 + col * 8192 + kg * 32);
  const unsigned vX1 = vX0 + 16 * 8192;

  f32x4 acc0[8], acc1[8];  // [half*4+et]
#pragma unroll
  for (int i = 0; i < 8; ++i) { acc0[i] = (f32x4)0.f; acc1[i] = (f32x4)0.f; }

  f32x4 xE[4], xO[4];

#define LOADX(xS, t)                          \
  do {                                        \
    const char* sX_ = sX + (size_t)(t) * 128; \
    GL4(xS[0], vX0, sX_, 0);                  \
    GL4(xS[1], vX0, sX_, 16);                 \
    GL4(xS[2], vX1, sX_, 0);                  \
    GL4(xS[3], vX1, sX_, 16);                 \
  } while (0)

  // stage this wave's 3 frags of step t into ring buffer buf (wave-uniform LDS dest)
#define STAGE(t, buf)                                                        \
  do {                                                                       \
    _Pragma("unroll") for (int c = 0; c < 3; ++c) {                          \
      const int f_ = w * 3 + c;                                              \
      const char* g_ = wfB + (size_t)(t) * 12288 + f_ * 1024 + l * 16;       \
      __builtin_amdgcn_global_load_lds(                                      \
          (const __attribute__((address_space(1))) void*)g_,                 \
          (__attribute__((address_space(3))) void*)&ldsB[buf][f_][0], 16, 0, 0); \
    }                                                                        \
  } while (0)

  // read all 12 frags of buffer buf and do 48 MFMAs with X set xS
#define CRUNCH(buf, xS)                                                      \
  do {                                                                       \
    bf16x8 ah0, am0, al0, ah1, am1, al1;                                     \
    split3(xS[0], xS[1], ah0, am0, al0);                                     \
    split3(xS[2], xS[3], ah1, am1, al1);                                     \
    const uint4* fb_ = &ldsB[buf][0][0];                                     \
    uint4 f0 = fb_[0 * 64 + l], f1 = fb_[1 * 64 + l], f2 = fb_[2 * 64 + l];  \
    uint4 f3 = fb_[3 * 64 + l], f4 = fb_[4 * 64 + l], f5 = fb_[5 * 64 + l];  \
    uint4 f6 = fb_[6 * 64 + l], f7 = fb_[7 * 64 + l], f8 = fb_[8 * 64 + l];  \
    uint4 f9 = fb_[9 * 64 + l], f10 = fb_[10 * 64 + l], f11 = fb_[11 * 64 + l]; \
    MM(acc0[0], ah0, f0); MM(acc0[4], ah1, f0);                              \
    MM(acc0[1], ah0, f3); MM(acc0[5], ah1, f3);                              \
    MM(acc0[2], ah0, f6); MM(acc0[6], ah1, f6);                              \
    MM(acc0[3], ah0, f9); MM(acc0[7], ah1, f9);                              \
    MM(acc1[0], ah0, f1); MM(acc1[4], ah1, f1);                              \
    MM(acc1[1], ah0, f4); MM(acc1[5], ah1, f4);                              \
    MM(acc1[2], ah0, f7); MM(acc1[6], ah1, f7);                              \
    MM(acc1[3], ah0, f10); MM(acc1[7], ah1, f10);                            \
    MM(acc1[0], am0, f0); MM(acc1[4], am1, f0);                              \
    MM(acc1[1], am0, f3); MM(acc1[5], am1, f3);                              \
    MM(acc1[2], am0, f6); MM(acc1[6], am1, f6);                              \
    MM(acc1[3], am0, f9); MM(acc1[7], am1, f9);                              \
    MM(acc1[0], ah0, f2); MM(acc1[4], ah1, f2);                              \
    MM(acc1[1], ah0, f5); MM(acc1[5], ah1, f5);                              \
    MM(acc1[2], ah0, f8); MM(acc1[6], ah1, f8);                              \
    MM(acc1[3], ah0, f11); MM(acc1[7], ah1, f11);                            \
    MM(acc1[0], al0, f0); MM(acc1[4], al1, f0);                              \
    MM(acc1[1], al0, f3); MM(acc1[5], al1, f3);                              \
    MM(acc1[2], al0, f6); MM(acc1[6], al1, f6);                              \
    MM(acc1[3], al0, f9); MM(acc1[7], al1, f9);                              \
    MM(acc1[0], am0, f1); MM(acc1[4], am1, f1);                              \
    MM(acc1[1], am0, f4); MM(acc1[5], am1, f4);                              \
    MM(acc1[2], am0, f7); MM(acc1[6], am1, f7);                              \
    MM(acc1[3], am0, f10); MM(acc1[7], am1, f10);                            \
  } while (0)

  // prologue: 2 steps in flight; per-wave vmem queue: s0(3) s1(3) x0(4) x1(4) = 14
  STAGE(0, 0);
  STAGE(1, 1);
  LOADX(xE, 0);
  LOADX(xO, 1);

#pragma unroll 1
  for (int t = 0; t < TSTEPS - 2; t += 2) {  // t = 0,2,...,12
    // even step t
    STAGE(t + 2, (t + 2) & 3);  // ring-4: target last read at t-2, all waves past barrier(t-1)
    WAITV(7);                   // retires through x(t): queue x(t),s(t+1),x(t+1),s(t+2)
    SB0;
    FENCE; BAR; FENCE;          // all waves' stage(t) landed
    CRUNCH(t & 3, xE);
    LOADX(xE, t + 2);           // refill consumed X regs
    // odd step t+1
    STAGE(t + 3, (t + 3) & 3);
    WAITV(7);
    SB0;
    FENCE; BAR; FENCE;
    CRUNCH((t + 1) & 3, xO);
    LOADX(xO, t + 3);
  }
  // tail: steps 14, 15 — queue: x14(4) s15(3) x15(4)
  WAITV(4);                     // retires x14 (+s15)
  SB0;
  FENCE; BAR; FENCE;
  CRUNCH(2, xE);
  WAITV(0);
  SB0;
  FENCE; BAR; FENCE;
  CRUNCH(3, xO);

  // write partials: Part[ks][tok][e]; C/D layout col=lane&15, row=(lane>>4)*4+q
#pragma unroll
  for (int half = 0; half < 2; ++half)
#pragma unroll
    for (int q = 0; q < 4; ++q) {
      const int tok = tokw + half * 16 + kg * 4 + q;
      float* dst = Part + ((size_t)ks * N_TOK + tok) * E_DIM + col;
#pragma unroll
      for (int et = 0; et < 4; ++et)
        dst[et * 16] = acc0[half * 4 + et][q] + acc1[half * 4 + et][q];
    }
}

// Kernel B: fixed-order 4-way reduce + validated ballot top-8 + softmax + scatter.
__global__ __launch_bounds__(256)
void reduce_router(const float* __restrict__ Part,
                   float* __restrict__ Pout, float* __restrict__ Mout) {
  const int lane = threadIdx.x & 63;
  const int gw = blockIdx.x * 4 + (threadIdx.x >> 6);  // 2048 waves

#pragma unroll 1
  for (int j = 0; j < 8; ++j) {
    const int tok = gw * 8 + j;
    const size_t base = (size_t)tok * E_DIM + lane;
    float v = Part[base];
    v += Part[(size_t)1 * N_TOK * E_DIM + base];
    v += Part[(size_t)2 * N_TOK * E_DIM + base];
    v += Part[(size_t)3 * N_TOK * E_DIM + base];

    float topv[K_TOP];
    int topi[K_TOP];
#pragma unroll
    for (int kk = 0; kk < K_TOP; ++kk) {
      float m = v;
#pragma unroll
      for (int off = 32; off > 0; off >>= 1)
        m = fmaxf(m, __shfl_xor(m, off, 64));
      const unsigned long long bal = __ballot(v == m);
      const int li = __ffsll(bal) - 1;  // lowest expert on ties == jax stable order
      topv[kk] = m;
      topi[kk] = li;
      if (lane == li) v = -INFINITY;
    }

    float p[K_TOP], sum = 0.f;
#pragma unroll
    for (int kk = 0; kk < K_TOP; ++kk) {
      p[kk] = expf(topv[kk] - topv[0]);
      sum += p[kk];
    }
    const float inv = 1.f / sum;

    float pv = 0.f, mv = 0.f;
#pragma unroll
    for (int kk = 0; kk < K_TOP; ++kk)
      if (topi[kk] == lane) { pv = p[kk] * inv; mv = 1.f; }

    Pout[(size_t)tok * E_DIM + lane] = pv;
    Mout[(size_t)tok * E_DIM + lane] = mv;
  }
}

extern "C" void kernel_launch(void* const* d_in, const int* in_sizes, int n_in,
                              void* d_out, int out_size, void* d_ws, size_t ws_size,
                              hipStream_t stream) {
  const float* X = (const float*)d_in[0];
  const float* W = (const float*)d_in[1];
  float* P = (float*)d_out;
  float* M = P + (size_t)N_TOK * E_DIM;

  uint4* WF = (uint4*)d_ws;                                 // 768 KB at offset 0
  float* Part = (float*)((char*)d_ws + (size_t)(1 << 20));  // 16 MB at offset 1 MB

  wprep_kernel<<<dim3(64), dim3(256), 0, stream>>>(W, WF);
  gemm_partial<<<dim3(512), dim3(256), 0, stream>>>(X, WF, Part);
  reduce_router<<<dim3(512), dim3(256), 0, stream>>>(Part, P, M);
}